// Round 13
// baseline (732.904 us; speedup 1.0000x reference)
//
#include <hip/hip_runtime.h>

#define NDIM  2048
#define WAVES 32
#define BCOLS 2176            // 0..2048 valid + pad
#define SLOTS 2128            // 2112 steps + pad
#define ENCB  0x40000000
#define SENTV 0xFFFFFFFFFFFFFFFFull

typedef unsigned long long u64;

// Static scratch: prep kernels rewrite everything main relies on, every launch.
// g_S4[w][sidx][lane] = {exp theta[w*64+lane][sidx-lane][0..2], 0}
__device__ __align__(16) float4 g_S4[(size_t)WAVES * SLOTS * 64];
__device__ __align__(16) u64    g_B[(size_t)(WAVES+1) * BCOLS * 2]; // boundary handoff

__device__ __forceinline__ u64 ald(const u64* p) {
  return __hip_atomic_load(p, __ATOMIC_RELAXED, __HIP_MEMORY_SCOPE_AGENT);
}
__device__ __forceinline__ void ast(u64* p, u64 v) {
  __hip_atomic_store(p, v, __ATOMIC_RELAXED, __HIP_MEMORY_SCOPE_AGENT);
}
// shift-up-by-1 across the wave via DPP wave_shr1 (verified working).
__device__ __forceinline__ float shup1(float x) {
  int v = __builtin_amdgcn_update_dpp(0, __float_as_int(x), 0x138, 0xf, 0xf, false);
  return __int_as_float(v);
}
// DPP helper: max(m, dpp(m, CTRL)) with old=m (invalid lanes keep m).
// CTRL must be a compile-time constant -> template parameter (R12 fix).
template <int CTRL>
__device__ __forceinline__ float maxdpp(float m) {
  int v = __builtin_amdgcn_update_dpp(__float_as_int(m), __float_as_int(m),
                                      CTRL, 0xf, 0xf, false);
  return fmaxf(m, __int_as_float(v));
}
__device__ __forceinline__ int imax(int a, int b) { return a > b ? a : b; }

// global -> LDS direct DMA, 16B per lane (R9-verified).
typedef const __attribute__((address_space(1))) void GV;
typedef __attribute__((address_space(3)))       void LV;
__device__ __forceinline__ void gll16(const void* g, void* l) {
  __builtin_amdgcn_global_load_lds((GV*)g, (LV*)l, 16, 0, 0);
}

// ---------------- prep A: exp(theta) transposed into staircase order --------
__global__ void vit_prep_theta(const float* __restrict__ theta) {
  const int tid = blockIdx.x * blockDim.x + threadIdx.x;
  const int stride = gridDim.x * blockDim.x;
  const int total = WAVES * SLOTS * 64;
  for (int i = tid; i < total; i += stride) {
    const int l    = i & 63;
    const int rest = i >> 6;
    const int s    = rest % SLOTS;
    const int w    = rest / SLOTS;
    const int row  = w * 64 + l;
    const int col  = s - l;
    float4 r = make_float4(0.f, 0.f, 0.f, 0.f);
    if (col >= 0 && col < NDIM) {
      const float* tp = theta + ((size_t)row * NDIM + col) * 3;
      r.x = __expf(tp[0]); r.y = __expf(tp[1]); r.z = __expf(tp[2]);
    }
    g_S4[i] = r;
  }
}

// ---------------- prep B: sentinel/boundary init ---------------------------
__global__ void vit_prep_bnd() {
  const int tid = blockIdx.x * blockDim.x + threadIdx.x;
  const int stride = gridDim.x * blockDim.x;
  const int nb = (WAVES+1) * BCOLS;
  const u64 hi0 = ((u64)(unsigned)ENCB) << 32;   // (Y=0, e=0)
  for (int i = tid; i < nb; i += stride) {
    int w = i / BCOLS;
    int c = i - w * BCOLS;
    u64 lo, hi;
    if (c > NDIM)    { lo = 0ull; hi = hi0; }                                   // pad cols
    else if (w == 0) { lo = (c == 0) ? (u64)__float_as_uint(1.0f) : 0ull; hi = hi0; } // row 0
    else if (c == 0) { lo = 0ull; hi = hi0; }                                   // V[i,0] = -inf
    else             { lo = SENTV; hi = SENTV; }                                // to be produced
    ast(&g_B[(size_t)i*2],   lo);
    ast(&g_B[(size_t)i*2+1], hi);
  }
}

// ---------------- main: 32 waves, striped wavefront, exp-space -------------
// R9 LDS skeleton (verified) + R11 lean STEP (verified) + cycle diet:
//  - rescale wave-max via DPP v_max tree (row_shr1/2/4/8 + bcast15/31) +
//    readlane63 + SALU exponent  (replaces 6 ds_bpermute shfl_xor)
//  - scale-prep gated by ONE __ballot(dsl>0); slow reduce only in rare adopt
//  - boundary stripe prefetched one block ahead
__global__ void __launch_bounds__(64, 1)
__attribute__((amdgpu_waves_per_eu(1, 1)))
vit_main(const float* __restrict__ A, float* __restrict__ out) {
  __shared__ float4 sT[2048];           // 2 buf x 16 slots x 64 lanes = 32KB
  const int lane = threadIdx.x;
  const int w    = blockIdx.x;
  const bool isL0 = (lane == 0);
  const int lsel = lane & 15;

  const float a00 = __expf(A[0]), a01 = __expf(A[1]), a02 = __expf(A[2]);
  const float a10 = __expf(A[3]), a11 = __expf(A[4]), a12 = __expf(A[5]);
  const float a20 = __expf(A[6]), a21 = __expf(A[7]), a22 = __expf(A[8]);

  const float4* tb4 = g_S4 + (size_t)w * SLOTS * 64 + lane;
  u64* bin  = g_B + (size_t)w     * BCOLS * 2;
  u64* bout = g_B + (size_t)(w+1) * BCOLS * 2;

  // state: own row col j-1 (p), row-above col j (u), row-above col j-1 (ud)
  float Mp=0.f,Xp=0.f,Yp=0.f, Mu=0.f,Xu=0.f,Yu=0.f, Mud=0.f,Xud=0.f,Yud=0.f;
  int e_w = 0;   // wave scale: registers hold value * 2^-e_w (wave-uniform)

  // boundary stripe prefetch, block 0: lane u (=lsel) holds col 2+u.
  u64* rpn;
  u64 cLo, cHi;
  {
    u64* rp0 = bin + (size_t)(2 + lsel) * 2;
    cLo = ald(rp0); cHi = ald(rp0 + 1);
    rpn = rp0 + 32;
  }
  // prologue: stage theta block 0 into LDS buffer 0
  #pragma unroll
  for (int u_ = 0; u_ < 16; ++u_)
    gll16(tb4 + (size_t)u_ * 64, &sT[u_ * 64]);

  // col 0 -> ud (prefilled, never sentinel)
  {
    u64 lo = ald(bin), hi = ald(bin + 1);
    while (lo == SENTV || hi == SENTV) { __builtin_amdgcn_s_sleep(2); lo = ald(bin); hi = ald(bin+1); }
    if (isL0) {
      Mud = __uint_as_float((unsigned)lo);
      Xud = __uint_as_float((unsigned)(lo >> 32));
      Yud = __uint_as_float((unsigned)hi);
    }
  }
  // col 1 -> u (spin = pipeline fill)
  {
    u64 lo = ald(bin + 2), hi = ald(bin + 3);
    while (lo == SENTV || hi == SENTV) { __builtin_amdgcn_s_sleep(8); lo = ald(bin+2); hi = ald(bin+3); }
    int ep = (int)((unsigned)(hi >> 32) - (unsigned)ENCB);
    int dd = ep - e_w;
    if (__builtin_amdgcn_readfirstlane(dd) > 48) { e_w = ep; dd = 0; } // states are zero
    if (isL0) {
      Mu = ldexpf(__uint_as_float((unsigned)lo), dd);
      Xu = ldexpf(__uint_as_float((unsigned)(lo >> 32)), dd);
      Yu = ldexpf(__uint_as_float((unsigned)hi), dd);
    }
  }

// STEP: SM=1 -> unconditional lane-63 store; SM=0 -> s>=64 guard.
// TM=1 -> terminal check (final block only). Theta from LDS ring reg DV.
#define STEPC(U, DV, SM, TM)                                                   \
  {                                                                            \
    const int s = base + (U) + 1;           /* lane computes col j = s-lane */ \
    float mn = DV.x * fmaf(a02, Yud, fmaf(a01, Xud, a00*Mud));                 \
    float xn = DV.y * fmaf(a12, Yu,  fmaf(a11, Xu,  a10*Mu));                  \
    float yn = DV.z * fmaf(a22, Yp,  fmaf(a21, Xp,  a20*Mp));                  \
    if ((SM) ? (lane == 63) : (s >= 64 && lane == 63)) {                       \
      u64 slo = ((u64)__float_as_uint(xn) << 32) | __float_as_uint(mn);        \
      u64 shi = ((u64)(unsigned)(e_w + ENCB) << 32) | __float_as_uint(yn);     \
      ast(bO + (size_t)(U)*2,     slo);                                        \
      ast(bO + (size_t)(U)*2 + 1, shi);                                        \
    }                                                                          \
    if ((TM) && s == 2111 && w == 31 && lane == 63) {                          \
      out[0] = (log2f(mn + xn + yn) + (float)e_w) * 0.69314718055994531f;      \
    }                                                                          \
    /* boundary consume for col s+1: pre-scaled stripe, lane (U) -> SGPR */    \
    const float rM = __int_as_float(__builtin_amdgcn_readlane(__float_as_int(Mbf), (U))); \
    const float rX = __int_as_float(__builtin_amdgcn_readlane(__float_as_int(Xbf), (U))); \
    const float rY = __int_as_float(__builtin_amdgcn_readlane(__float_as_int(Ybf), (U))); \
    /* rotate */                                                               \
    Mud = Mu; Xud = Xu; Yud = Yu;                                              \
    const float sm = shup1(mn);                                                \
    const float sx = shup1(xn);                                                \
    const float sy = shup1(yn);                                                \
    Mu = isL0 ? rM : sm;                                                       \
    Xu = isL0 ? rX : sx;                                                       \
    Yu = isL0 ? rY : sy;                                                       \
    Mp = mn; Xp = xn; Yp = yn;                                                 \
  }
#define STEPR(U, DV, SM, TM) STEPC(U, DV, SM, TM) DV = sT[ldsA + ((U)+4)*64 + lane];

#define BLOCK(SM, TM)                                                          \
  {                                                                            \
    const unsigned ldsA = ((unsigned)(base >> 4) & 1u) << 10;                  \
    const unsigned ldsB = ldsA ^ 1024u;                                        \
    /* ---- validate prefetched stripe (cols base+2 .. base+17) ---- */        \
    u64* rpc_ = rpn - 32;                                                      \
    bool bad_ = (cLo == SENTV) || (cHi == SENTV);                              \
    while (__ballot(bad_)) {                                                   \
      __builtin_amdgcn_s_sleep(1);                                             \
      cLo = ald(rpc_); cHi = ald(rpc_ + 1);                                    \
      bad_ = (cLo == SENTV) || (cHi == SENTV);                                 \
    }                                                                          \
    /* ---- fence: prev gll batch (-> ldsA) complete before ds_read ---- */    \
    __builtin_amdgcn_s_waitcnt(0x0F70);  /* vmcnt(0) only */                   \
    __builtin_amdgcn_sched_barrier(0);                                         \
    /* ---- prefetch next stripe + stage next theta into ldsB ---- */          \
    u64 nLo = ald(rpn), nHi = ald(rpn + 1);                                    \
    rpn += 32;                                                                 \
    {                                                                          \
      const float4* tn_ = tb4 + (size_t)(base + 16) * 64;                      \
      _Pragma("unroll")                                                        \
      for (int u_ = 0; u_ < 16; ++u_)                                          \
        gll16(tn_ + (size_t)u_ * 64, &sT[ldsB + u_ * 64]);                     \
    }                                                                          \
    __builtin_amdgcn_sched_barrier(0);                                         \
    /* ---- scale prep: ballot-gated; injected dsl <= 0 always ---- */         \
    int dsl = ((int)(unsigned)(cHi >> 32) - ENCB) - e_w;                       \
    if (__ballot(dsl > 0)) {          /* rare adopt path */                    \
      int dm = dsl;                                                            \
      dm = imax(dm, __shfl_xor(dm, 1));                                        \
      dm = imax(dm, __shfl_xor(dm, 2));                                        \
      dm = imax(dm, __shfl_xor(dm, 4));                                        \
      dm = imax(dm, __shfl_xor(dm, 8));                                        \
      const int sh = -dm;                                                      \
      Mp = ldexpf(Mp,sh); Xp = ldexpf(Xp,sh); Yp = ldexpf(Yp,sh);              \
      Mu = ldexpf(Mu,sh); Xu = ldexpf(Xu,sh); Yu = ldexpf(Yu,sh);              \
      Mud= ldexpf(Mud,sh);Xud= ldexpf(Xud,sh);Yud= ldexpf(Yud,sh);             \
      e_w += dm; dsl -= dm;                                                    \
    }                                                                          \
    const float Mbf = ldexpf(__uint_as_float((unsigned)cLo), dsl);             \
    const float Xbf = ldexpf(__uint_as_float((unsigned)(cLo >> 32)), dsl);     \
    const float Ybf = ldexpf(__uint_as_float((unsigned)cHi), dsl);             \
    /* ---- ds prologue: slots 0..3 of ldsA ---- */                            \
    float4 d0 = sT[ldsA + 0*64 + lane];                                        \
    float4 d1 = sT[ldsA + 1*64 + lane];                                        \
    float4 d2 = sT[ldsA + 2*64 + lane];                                        \
    float4 d3 = sT[ldsA + 3*64 + lane];                                        \
    /* ---- 16 steps ---- */                                                   \
    u64* bO = bout + (size_t)(base - 62) * 2;                                  \
    STEPR(0, d0, SM, TM)  STEPR(1, d1, SM, TM)                                 \
    STEPR(2, d2, SM, TM)  STEPR(3, d3, SM, TM)                                 \
    STEPR(4, d0, SM, TM)  STEPR(5, d1, SM, TM)                                 \
    STEPR(6, d2, SM, TM)  STEPR(7, d3, SM, TM)                                 \
    STEPR(8, d0, SM, TM)  STEPR(9, d1, SM, TM)                                 \
    STEPR(10, d2, SM, TM) STEPR(11, d3, SM, TM)                                \
    STEPC(12, d0, SM, TM) STEPC(13, d1, SM, TM)                                \
    STEPC(14, d2, SM, TM) STEPC(15, d3, SM, TM)                                \
    /* ---- epoch rescale: DPP max tree + SALU exponent ---- */                \
    {                                                                          \
      float m = fmaxf(fmaxf(Mp, Xp), Yp);                                      \
      const int jl = base + 16 - lane;                                         \
      if (jl < 1 || jl > NDIM) m = 0.0f;                                       \
      m = maxdpp<0x111>(m);   /* row_shr:1  */                                 \
      m = maxdpp<0x112>(m);   /* row_shr:2  */                                 \
      m = maxdpp<0x114>(m);   /* row_shr:4  */                                 \
      m = maxdpp<0x118>(m);   /* row_shr:8  */                                 \
      m = maxdpp<0x142>(m);   /* row_bcast:15 */                               \
      m = maxdpp<0x143>(m);   /* row_bcast:31 -> lane 63 = wave max */         \
      const int mb = __builtin_amdgcn_readlane(__float_as_int(m), 63);         \
      int E = ((mb >> 23) & 0xFF) - 127;                                       \
      if (mb == 0) E = 0;                                                      \
      const int sh = -E;                                                       \
      Mp = ldexpf(Mp,sh); Xp = ldexpf(Xp,sh); Yp = ldexpf(Yp,sh);              \
      Mu = ldexpf(Mu,sh); Xu = ldexpf(Xu,sh); Yu = ldexpf(Yu,sh);              \
      Mud= ldexpf(Mud,sh);Xud= ldexpf(Xud,sh);Yud= ldexpf(Yud,sh);             \
      e_w += E;                                                                \
    }                                                                          \
    base += 16; cLo = nLo; cHi = nHi;                                          \
  }

  int base = 0;
  // blocks 0..3: s>=64 store guard active
  BLOCK(0, 0) BLOCK(0, 0) BLOCK(0, 0) BLOCK(0, 0)
  // blocks 4..130: unconditional lane-63 store
  for (int it = 0; it < 127; ++it) { BLOCK(1, 0) }
  // block 131: terminal check active
  BLOCK(1, 1)
#undef BLOCK
#undef STEPR
#undef STEPC
}

extern "C" void kernel_launch(void* const* d_in, const int* in_sizes, int n_in,
                              void* d_out, int out_size, void* d_ws, size_t ws_size,
                              hipStream_t stream) {
  const float* theta = (const float*)d_in[0];
  const float* A     = (const float*)d_in[1];
  float* out = (float*)d_out;
  (void)in_sizes; (void)n_in; (void)out_size; (void)d_ws; (void)ws_size;
  vit_prep_theta<<<dim3(8192), dim3(256), 0, stream>>>(theta);
  vit_prep_bnd<<<dim3(256), dim3(256), 0, stream>>>();
  vit_main<<<dim3(WAVES), dim3(64), 0, stream>>>(A, out);
}

// Round 14
// 628.738 us; speedup vs baseline: 1.1657x; 1.1657x over previous
//
#include <hip/hip_runtime.h>

#define NDIM  2048
#define WAVES 32
#define BCOLS 2176            // 0..2048 valid + pad
#define SLOTS 2128            // 2112 steps + pad
#define ENCB  0x40000000
#define SENTV 0xFFFFFFFFFFFFFFFFull

typedef unsigned long long u64;

// Static scratch: prep kernels rewrite everything main relies on, every launch.
// g_S4[w][sidx][lane] = {exp theta[w*64+lane][sidx-lane][0..2], 0}
__device__ __align__(16) float4 g_S4[(size_t)WAVES * SLOTS * 64];
__device__ __align__(16) u64    g_B[(size_t)(WAVES+1) * BCOLS * 2]; // boundary handoff

__device__ __forceinline__ u64 ald(const u64* p) {
  return __hip_atomic_load(p, __ATOMIC_RELAXED, __HIP_MEMORY_SCOPE_AGENT);
}
__device__ __forceinline__ void ast(u64* p, u64 v) {
  __hip_atomic_store(p, v, __ATOMIC_RELAXED, __HIP_MEMORY_SCOPE_AGENT);
}
// shift-up-by-1 across the wave via DPP wave_shr1 (verified working).
__device__ __forceinline__ float shup1(float x) {
  int v = __builtin_amdgcn_update_dpp(0, __float_as_int(x), 0x138, 0xf, 0xf, false);
  return __int_as_float(v);
}
// DPP helper: max(m, dpp(m, CTRL)) with old=m (invalid lanes keep m).
template <int CTRL>
__device__ __forceinline__ float maxdpp(float m) {
  int v = __builtin_amdgcn_update_dpp(__float_as_int(m), __float_as_int(m),
                                      CTRL, 0xf, 0xf, false);
  return fmaxf(m, __int_as_float(v));
}
__device__ __forceinline__ int imax(int a, int b) { return a > b ? a : b; }

// ---------------- prep A: exp(theta) transposed into staircase order --------
__global__ void vit_prep_theta(const float* __restrict__ theta) {
  const int tid = blockIdx.x * blockDim.x + threadIdx.x;
  const int stride = gridDim.x * blockDim.x;
  const int total = WAVES * SLOTS * 64;
  for (int i = tid; i < total; i += stride) {
    const int l    = i & 63;
    const int rest = i >> 6;
    const int s    = rest % SLOTS;
    const int w    = rest / SLOTS;
    const int row  = w * 64 + l;
    const int col  = s - l;
    float4 r = make_float4(0.f, 0.f, 0.f, 0.f);
    if (col >= 0 && col < NDIM) {
      const float* tp = theta + ((size_t)row * NDIM + col) * 3;
      r.x = __expf(tp[0]); r.y = __expf(tp[1]); r.z = __expf(tp[2]);
    }
    g_S4[i] = r;
  }
}

// ---------------- prep B: sentinel/boundary init ---------------------------
__global__ void vit_prep_bnd() {
  const int tid = blockIdx.x * blockDim.x + threadIdx.x;
  const int stride = gridDim.x * blockDim.x;
  const int nb = (WAVES+1) * BCOLS;
  const u64 hi0 = ((u64)(unsigned)ENCB) << 32;   // (Y=0, e=0)
  for (int i = tid; i < nb; i += stride) {
    int w = i / BCOLS;
    int c = i - w * BCOLS;
    u64 lo, hi;
    if (c > NDIM)    { lo = 0ull; hi = hi0; }                                   // pad cols
    else if (w == 0) { lo = (c == 0) ? (u64)__float_as_uint(1.0f) : 0ull; hi = hi0; } // row 0
    else if (c == 0) { lo = 0ull; hi = hi0; }                                   // V[i,0] = -inf
    else             { lo = SENTV; hi = SENTV; }                                // to be produced
    ast(&g_B[(size_t)i*2],   lo);
    ast(&g_B[(size_t)i*2+1], hi);
  }
}

// per-dword sentinel test (handoff is now a 16-lane batched store; per-dword
// check makes any partial visibility read as not-ready)
__device__ __forceinline__ bool isbad(u64 lo, u64 hi) {
  return ((unsigned)lo == 0xFFFFFFFFu) || ((unsigned)(lo >> 32) == 0xFFFFFFFFu) ||
         ((unsigned)hi == 0xFFFFFFFFu) || ((unsigned)(hi >> 32) == 0xFFFFFFFFu);
}

// ---------------- main: 32 waves, striped wavefront, exp-space -------------
// R11 structure (best measured, 563us vit_main) with:
//  - DPP max-tree rescale + ballot-gated scale prep (R13, verified correct)
//  - BATCHED handoff: per step lane63 writes 16B to LDS bounce; at block end
//    lanes 0..15 issue 2 wave-level atomic u64 stores (32 VMEM stores/block
//    -> 2). Theory: coherent same-line store retirement was backpressuring
//    the vmcnt queue (~150cy/step) — the invariant cost across R1-R13.
__global__ void __launch_bounds__(64, 1)
__attribute__((amdgpu_waves_per_eu(1, 1)))
vit_main(const float* __restrict__ A, float* __restrict__ out) {
  __shared__ float4 sB[16];   // handoff bounce (256B)
  const int lane = threadIdx.x;
  const int w    = blockIdx.x;
  const bool isL0 = (lane == 0);
  const int lsel = lane & 15;

  const float a00 = __expf(A[0]), a01 = __expf(A[1]), a02 = __expf(A[2]);
  const float a10 = __expf(A[3]), a11 = __expf(A[4]), a12 = __expf(A[5]);
  const float a20 = __expf(A[6]), a21 = __expf(A[7]), a22 = __expf(A[8]);

  const float4* tb4 = g_S4 + (size_t)w * SLOTS * 64 + lane;
  u64* bin  = g_B + (size_t)w     * BCOLS * 2;
  u64* bout = g_B + (size_t)(w+1) * BCOLS * 2;

  // state: own row col j-1 (p), row-above col j (u), row-above col j-1 (ud)
  float Mp=0.f,Xp=0.f,Yp=0.f, Mu=0.f,Xu=0.f,Yu=0.f, Mud=0.f,Xud=0.f,Yud=0.f;
  int e_w = 0;   // wave scale: registers hold value * 2^-e_w (wave-uniform)

  // ---- theta block 0 (slots 0..15) into named regs ----
  float4 Ta0  = tb4[0*64],  Ta1  = tb4[1*64],  Ta2  = tb4[2*64],  Ta3  = tb4[3*64];
  float4 Ta4  = tb4[4*64],  Ta5  = tb4[5*64],  Ta6  = tb4[6*64],  Ta7  = tb4[7*64];
  float4 Ta8  = tb4[8*64],  Ta9  = tb4[9*64],  Ta10 = tb4[10*64], Ta11 = tb4[11*64];
  float4 Ta12 = tb4[12*64], Ta13 = tb4[13*64], Ta14 = tb4[14*64], Ta15 = tb4[15*64];
  float4 Tb0  = make_float4(0,0,0,0), Tb1  = Tb0, Tb2  = Tb0, Tb3  = Tb0;
  float4 Tb4  = Tb0, Tb5  = Tb0, Tb6  = Tb0, Tb7  = Tb0;
  float4 Tb8  = Tb0, Tb9  = Tb0, Tb10 = Tb0, Tb11 = Tb0;
  float4 Tb12 = Tb0, Tb13 = Tb0, Tb14 = Tb0, Tb15 = Tb0;

  // ---- boundary ring: lane-striped. Block k group = cols k*16+2..k*16+17,
  //      lane u (=lsel) holds col k*16+2+u. Preload block 0; rpn -> block 1.
  u64 cLoa, cHia, cLob = 0, cHib = 0;
  u64* rpn;
  {
    u64* rp0 = bin + (size_t)(2 + lsel) * 2;
    cLoa = ald(rp0); cHia = ald(rp0 + 1);
    rpn = rp0 + 32;
  }

  // col 0 -> ud (prefilled, never sentinel)
  {
    u64 lo = ald(bin), hi = ald(bin + 1);
    while (isbad(lo, hi)) { __builtin_amdgcn_s_sleep(2); lo = ald(bin); hi = ald(bin+1); }
    if (isL0) {
      Mud = __uint_as_float((unsigned)lo);
      Xud = __uint_as_float((unsigned)(lo >> 32));
      Yud = __uint_as_float((unsigned)hi);
    }
  }
  // col 1 -> u (spin = pipeline fill)
  {
    u64 lo = ald(bin + 2), hi = ald(bin + 3);
    while (isbad(lo, hi)) { __builtin_amdgcn_s_sleep(8); lo = ald(bin+2); hi = ald(bin+3); }
    int ep = (int)((unsigned)(hi >> 32) - (unsigned)ENCB);
    int dd = ep - e_w;
    if (__builtin_amdgcn_readfirstlane(dd) > 48) { e_w = ep; dd = 0; } // states are zero
    if (isL0) {
      Mu = ldexpf(__uint_as_float((unsigned)lo), dd);
      Xu = ldexpf(__uint_as_float((unsigned)(lo >> 32)), dd);
      Yu = ldexpf(__uint_as_float((unsigned)hi), dd);
    }
  }

// TM=1 -> terminal check (final block only).
#define STEP(U, S, TM)                                                         \
  {                                                                            \
    const int s = base + (U) + 1;           /* lane computes col j = s-lane */ \
    float mn = T##S##U.x * fmaf(a02, Yud, fmaf(a01, Xud, a00*Mud));            \
    float xn = T##S##U.y * fmaf(a12, Yu,  fmaf(a11, Xu,  a10*Mu));             \
    float yn = T##S##U.z * fmaf(a22, Yp,  fmaf(a21, Xp,  a20*Mp));             \
    /* handoff bounce: lane 63 -> LDS slot U (stored to global at block end) */\
    if (lane == 63)                                                            \
      sB[U] = make_float4(mn, xn, yn, __int_as_float(e_w + ENCB));             \
    if ((TM) && s == 2111 && w == 31 && lane == 63) {                          \
      out[0] = (log2f(mn + xn + yn) + (float)e_w) * 0.69314718055994531f;      \
    }                                                                          \
    /* boundary consume for col s+1: pre-scaled stripe, lane (U) -> SGPR */    \
    const float rM = __int_as_float(__builtin_amdgcn_readlane(__float_as_int(Mbf), (U))); \
    const float rX = __int_as_float(__builtin_amdgcn_readlane(__float_as_int(Xbf), (U))); \
    const float rY = __int_as_float(__builtin_amdgcn_readlane(__float_as_int(Ybf), (U))); \
    /* rotate */                                                               \
    Mud = Mu; Xud = Xu; Yud = Yu;                                              \
    const float sm = shup1(mn);                                                \
    const float sx = shup1(xn);                                                \
    const float sy = shup1(yn);                                                \
    Mu = isL0 ? rM : sm;                                                       \
    Xu = isL0 ? rX : sx;                                                       \
    Yu = isL0 ? rY : sy;                                                       \
    Mp = mn; Xp = xn; Yp = yn;                                                 \
  }

#define BLOCK(S, SN, TM)                                                       \
  {                                                                            \
    /* ---- validate ring S (cols base+2 .. base+17, striped) ---- */          \
    u64* rpc_ = rpn - 32;                                                      \
    bool bad_ = isbad(cLo##S, cHi##S);                                         \
    while (__ballot(bad_)) {                                                   \
      __builtin_amdgcn_s_sleep(1);                                             \
      cLo##S = ald(rpc_); cHi##S = ald(rpc_ + 1);                              \
      bad_ = isbad(cLo##S, cHi##S);                                            \
    }                                                                          \
    /* ---- stage block k+1 theta into the other reg set ---- */               \
    {                                                                          \
      const float4* tn_ = tb4 + (size_t)(base + 16) * 64;                      \
      T##SN##0  = tn_[0*64];  T##SN##1  = tn_[1*64];                           \
      T##SN##2  = tn_[2*64];  T##SN##3  = tn_[3*64];                           \
      T##SN##4  = tn_[4*64];  T##SN##5  = tn_[5*64];                           \
      T##SN##6  = tn_[6*64];  T##SN##7  = tn_[7*64];                           \
      T##SN##8  = tn_[8*64];  T##SN##9  = tn_[9*64];                           \
      T##SN##10 = tn_[10*64]; T##SN##11 = tn_[11*64];                          \
      T##SN##12 = tn_[12*64]; T##SN##13 = tn_[13*64];                          \
      T##SN##14 = tn_[14*64]; T##SN##15 = tn_[15*64];                          \
    }                                                                          \
    cLo##SN = ald(rpn); cHi##SN = ald(rpn + 1);                                \
    rpn += 32;                                                                 \
    /* ---- scale prep: ballot-gated; injected dsl <= 0 always ---- */         \
    int dsl = ((int)(unsigned)(cHi##S >> 32) - ENCB) - e_w;                    \
    if (__ballot(dsl > 0)) {          /* rare adopt path */                    \
      int dm = dsl;                                                            \
      dm = imax(dm, __shfl_xor(dm, 1));                                        \
      dm = imax(dm, __shfl_xor(dm, 2));                                        \
      dm = imax(dm, __shfl_xor(dm, 4));                                        \
      dm = imax(dm, __shfl_xor(dm, 8));                                        \
      const int sh = -dm;                                                      \
      Mp = ldexpf(Mp,sh); Xp = ldexpf(Xp,sh); Yp = ldexpf(Yp,sh);              \
      Mu = ldexpf(Mu,sh); Xu = ldexpf(Xu,sh); Yu = ldexpf(Yu,sh);              \
      Mud= ldexpf(Mud,sh);Xud= ldexpf(Xud,sh);Yud= ldexpf(Yud,sh);             \
      e_w += dm; dsl -= dm;                                                    \
    }                                                                          \
    const float Mbf = ldexpf(__uint_as_float((unsigned)cLo##S), dsl);          \
    const float Xbf = ldexpf(__uint_as_float((unsigned)(cLo##S >> 32)), dsl);  \
    const float Ybf = ldexpf(__uint_as_float((unsigned)cHi##S), dsl);          \
    __builtin_amdgcn_sched_barrier(0);                                         \
    /* ---- 16 steps (no global stores inside) ---- */                         \
    STEP(0,S,TM)  STEP(1,S,TM)  STEP(2,S,TM)  STEP(3,S,TM)                     \
    STEP(4,S,TM)  STEP(5,S,TM)  STEP(6,S,TM)  STEP(7,S,TM)                     \
    STEP(8,S,TM)  STEP(9,S,TM)  STEP(10,S,TM) STEP(11,S,TM)                    \
    STEP(12,S,TM) STEP(13,S,TM) STEP(14,S,TM) STEP(15,S,TM)                    \
    /* ---- batched handoff: lanes 0..15, 2 atomic u64 stores total ---- */    \
    {                                                                          \
      const int col_ = base - 62 + lane;                                       \
      if (lane < 16 && col_ >= 1) {                                            \
        float4 v = sB[lane];                                                   \
        u64 lo_ = ((u64)__float_as_uint(v.y) << 32) | __float_as_uint(v.x);    \
        u64 hi_ = ((u64)__float_as_uint(v.w) << 32) | __float_as_uint(v.z);    \
        u64* bO_ = bout + (size_t)col_ * 2;                                    \
        ast(bO_,     lo_);                                                     \
        ast(bO_ + 1, hi_);                                                     \
      }                                                                        \
    }                                                                          \
    /* ---- epoch rescale: DPP max tree + SALU exponent ---- */                \
    {                                                                          \
      float m = fmaxf(fmaxf(Mp, Xp), Yp);                                      \
      const int jl = base + 16 - lane;                                         \
      if (jl < 1 || jl > NDIM) m = 0.0f;                                       \
      m = maxdpp<0x111>(m);   /* row_shr:1  */                                 \
      m = maxdpp<0x112>(m);   /* row_shr:2  */                                 \
      m = maxdpp<0x114>(m);   /* row_shr:4  */                                 \
      m = maxdpp<0x118>(m);   /* row_shr:8  */                                 \
      m = maxdpp<0x142>(m);   /* row_bcast:15 */                               \
      m = maxdpp<0x143>(m);   /* row_bcast:31 -> lane 63 = wave max */         \
      const int mb = __builtin_amdgcn_readlane(__float_as_int(m), 63);         \
      int E = ((mb >> 23) & 0xFF) - 127;                                       \
      if (mb == 0) E = 0;                                                      \
      const int sh = -E;                                                       \
      Mp = ldexpf(Mp,sh); Xp = ldexpf(Xp,sh); Yp = ldexpf(Yp,sh);              \
      Mu = ldexpf(Mu,sh); Xu = ldexpf(Xu,sh); Yu = ldexpf(Yu,sh);              \
      Mud= ldexpf(Mud,sh);Xud= ldexpf(Xud,sh);Yud= ldexpf(Yud,sh);             \
      e_w += E;                                                                \
    }                                                                          \
    base += 16;                                                                \
  }

  int base = 0;
  // blocks 0..130 (store guard handles warmup cols automatically)
  BLOCK(a, b, 0) BLOCK(b, a, 0)
  for (int it = 0; it < 64; ++it) {
    BLOCK(a, b, 0)
    BLOCK(b, a, 0)
  }
  // final pair; terminal check only in block 131
  BLOCK(a, b, 0)
  BLOCK(b, a, 1)
#undef BLOCK
#undef STEP
}

extern "C" void kernel_launch(void* const* d_in, const int* in_sizes, int n_in,
                              void* d_out, int out_size, void* d_ws, size_t ws_size,
                              hipStream_t stream) {
  const float* theta = (const float*)d_in[0];
  const float* A     = (const float*)d_in[1];
  float* out = (float*)d_out;
  (void)in_sizes; (void)n_in; (void)out_size; (void)d_ws; (void)ws_size;
  vit_prep_theta<<<dim3(8192), dim3(256), 0, stream>>>(theta);
  vit_prep_bnd<<<dim3(256), dim3(256), 0, stream>>>();
  vit_main<<<dim3(WAVES), dim3(64), 0, stream>>>(A, out);
}